// Round 1
// baseline (121.495 us; speedup 1.0000x reference)
//
#include <hip/hip_runtime.h>

// R18: column-split quarter tiles (grid 2048 = b*4 + (sr*2+sc), 256 thr).
//   LDS 39.9 KB -> 28.1 KB => 5 blocks/CU (was 4), 2x blocks for backfill
//   across barrier drains. Theory: kernel is latency/occupancy-bound
//   (VALUBusy 40%, Mfma 4%, HBM 4%, Occ 30%).
//   k_fused: init zero hsu[4][30][36]; pack w2 -> bwl[768]; wp -> wps[128]
//     P1 conv1+relu+pool (interior fast path: no bounds checks for 93% tasks)
//        -> f16 tile hsu (rows 0..29 = pooled rows 28*sr-1..28*sr+28, cols same for sc)
//     P2 conv2+pool+relu via mfma_f32_16x16x32_f16, 49 patches (7x7), one chunk;
//        fv -> fsu rows; reduce via fdot2 -> pfl[196]
//     P3 fc1 partial via float4 dots (patch-granular gather) -> h1p[b][4][64]
//   k_tail: 1 wave/batch, shuffle-only fc2 + log_softmax (no LDS, no barriers)
// Pinned: (R14) no device-scope fence/atomic cross-block sync; (R15) no
// long-lived VGPR state (spills); WRITE_SIZE now 512 KB (h1p f32 x4 partials).
// hsu stride 36 == 4 (mod 32): A-read 16-lane group hits 16 distinct banks.

#define HSTR 36   // 30 cols used + 6 pad (u32 units); 36%32=4 -> conflict-free
#define NROWS 30  // 28 tile h-rows + 2 halo
#define FSTR 33   // fsu row stride in u32 (66 f16) -> conflict-free reduce

typedef _Float16 half2_t __attribute__((ext_vector_type(2)));
typedef _Float16 f16x8 __attribute__((ext_vector_type(8)));
typedef float f32x4 __attribute__((ext_vector_type(4)));
typedef float f32x2 __attribute__((ext_vector_type(2)));

__device__ __forceinline__ unsigned pack_f16(float a, float b) {
  union { half2_t h; unsigned u; } z;
  z.h[0] = (_Float16)a;
  z.h[1] = (_Float16)b;
  return z.u;
}

__device__ __forceinline__ half2_t as_h2(unsigned u) {
  union { unsigned u; half2_t h; } z;
  z.u = u;
  return z.h;
}

__device__ __forceinline__ f16x8 as_f16x8(uint4 u) {
  union { uint4 u; f16x8 f; } z;
  z.u = u;
  return z.f;
}

__device__ __forceinline__ float fdot2_(half2_t a, half2_t b, float c) {
#if __has_builtin(__builtin_amdgcn_fdot2)
  return __builtin_amdgcn_fdot2(a, b, c, false);
#else
  return c + (float)a[0] * (float)b[0] + (float)a[1] * (float)b[1];
#endif
}

__global__ __launch_bounds__(256, 5) void k_fused(
    const float* __restrict__ x, const float* __restrict__ w1,
    const float* __restrict__ b1, const float* __restrict__ w2,
    const float* __restrict__ b2, const float* __restrict__ wp,
    const float* __restrict__ bp, const float* __restrict__ w_fc1,
    float* __restrict__ h1p) {
  __shared__ __align__(16) unsigned hsu[4 * NROWS * HSTR];  // 17.3 KB
  __shared__ __align__(16) unsigned bwl[768];               // 3.0 KB B-frags
  __shared__ __align__(16) unsigned wps[128];               // 0.5 KB wp pairs [i][ot]
  __shared__ __align__(16) unsigned fsu[49 * FSTR];         // 6.3 KB (f16 rows)
  __shared__ __align__(16) float pfl[196];                  // 0.8 KB
  const int tid = threadIdx.x;
  const int b = blockIdx.x >> 2;
  const int tile = blockIdx.x & 3;
  const int sr = tile >> 1;
  const int sc = tile & 1;
  const int l = tid & 63;
  const int wv = __builtin_amdgcn_readfirstlane(tid >> 6);  // wave id 0..3
  const float* xb = x + (long)b * 12544;
  const float bpv = bp[tid & 3];

  for (int i = tid; i < 4 * NROWS * HSTR; i += 256) hsu[i] = 0u;
  // Pack conv2 weights into LDS: 3 entries per thread.
  for (int t = tid; t < 768; t += 256) {
    int oc = t / 48, k32 = t % 48;
    unsigned v = 0u;
    if (k32 < 36) {
      int icp = k32 / 9, tap = k32 - icp * 9;
      v = pack_f16(w2[(oc * 8 + 2 * icp) * 9 + tap],
                   w2[(oc * 8 + 2 * icp + 1) * 9 + tap]);
    }
    bwl[t] = v;
  }
  // Pack patch weights: wps[i*4+ot] = f16pair over lanes (2i, 2i+1) for ot.
  if (tid < 128) {
    int i = tid >> 2, ot = tid & 3;
    int l0 = 2 * i, l1 = 2 * i + 1;
    wps[tid] = pack_f16(wp[ot * 64 + (l0 & 15) * 4 + (l0 >> 4)],
                        wp[ot * 64 + (l1 & 15) * 4 + (l1 >> 4)]);
  }
  __syncthreads();

  // ---- P1: conv1(1->8)+bias+relu+maxpool2 (packed f32) -> f16 LDS tile ----
  // tile: 30x30 pooled-h cells, (r,c) -> global (28*sr-1+r, 28*sc-1+c)
  for (int task = tid; task < 900; task += 256) {
    int r = task / 30, c = task - r * 30;
    int gr = 28 * sr - 1 + r;
    int gc = 28 * sc - 1 + c;
    if ((unsigned)gr >= 56u || (unsigned)gc >= 56u) continue;
    float win[4][4];
    int iy0 = 2 * gr - 1, ix0 = 2 * gc - 1;
    if (gr >= 1 && gr <= 54 && gc >= 1 && gc <= 54) {
      // interior fast path: all 16 taps in-bounds, no cndmask chains
      const float* xp = xb + iy0 * 112 + ix0;
#pragma unroll
      for (int rr = 0; rr < 4; ++rr)
#pragma unroll
        for (int qq = 0; qq < 4; ++qq)
          win[rr][qq] = xp[rr * 112 + qq];
    } else {
#pragma unroll
      for (int rr = 0; rr < 4; ++rr) {
        int iy = iy0 + rr;
        bool yok = (unsigned)iy < 112u;
#pragma unroll
        for (int qq = 0; qq < 4; ++qq) {
          int ix = ix0 + qq;
          win[rr][qq] = (yok && (unsigned)ix < 112u) ? xb[iy * 112 + ix] : 0.f;
        }
      }
    }
    float hv[8];
#pragma unroll
    for (int ch = 0; ch < 8; ++ch) {
      f32x2 sA = {0.f, 0.f};  // (s00, s01)
      f32x2 sB = {0.f, 0.f};  // (s10, s11)
#pragma unroll
      for (int ty = 0; ty < 3; ++ty)
#pragma unroll
        for (int tx = 0; tx < 3; ++tx) {
          float wk = w1[ch * 9 + ty * 3 + tx];
          f32x2 wkk = {wk, wk};
          f32x2 xa = {win[ty][tx], win[ty][tx + 1]};
          f32x2 xb2 = {win[ty + 1][tx], win[ty + 1][tx + 1]};
          sA = __builtin_elementwise_fma(xa, wkk, sA);
          sB = __builtin_elementwise_fma(xb2, wkk, sB);
        }
      f32x2 sm = __builtin_elementwise_max(sA, sB);
      float m = fmaxf(sm.x, sm.y);
      hv[ch] = fmaxf(m + b1[ch], 0.f);
    }
#pragma unroll
    for (int cp = 0; cp < 4; ++cp)
      hsu[(cp * NROWS + r) * HSTR + c] = pack_f16(hv[2 * cp], hv[2 * cp + 1]);
  }
  __syncthreads();

  // ---- P2: conv2+pool+relu via MFMA; fv -> fsu; patch reduce -> pfl ----
  {
    const int q = l >> 4;  // k-octet / fmem role
    int offs[12];
#pragma unroll
    for (int kk = 0; kk < 3; ++kk)
#pragma unroll
      for (int i = 0; i < 4; ++i) {
        int k32 = kk * 16 + q * 4 + i;
        int icp = k32 / 9, tap = k32 - icp * 9;
        int ty = tap / 3, tx = tap - ty * 3;
        offs[kk * 4 + i] = (icp * NROWS + ty) * HSTR + tx;  // junk if k32>=36
      }
    const int yoff = 2 * ((l >> 3) & 1) + ((l >> 1) & 1);  // 2a+dy
    const int xoff = 2 * ((l >> 2) & 1) + (l & 1);         // 2b+dx
    uint4 bu0 = *(const uint4*)(bwl + (l & 15) * 48 + 0 * 16 + q * 4);
    uint4 bu1 = *(const uint4*)(bwl + (l & 15) * 48 + 1 * 16 + q * 4);
    uint4 bu2 = *(const uint4*)(bwl + (l & 15) * 48 + 2 * 16 + q * 4);
    const float b2v = b2[l & 15];
    _Float16* fsh = (_Float16*)fsu;

#pragma unroll 2
    for (int p_l = wv; p_l < 49; p_l += 4) {  // 7x7 local patches
      int py = p_l / 7, px = p_l - py * 7;
      int base = (4 * py + yoff) * HSTR + 4 * px + xoff;
      uint4 a0u, a1u, a2u = make_uint4(0u, 0u, 0u, 0u);
      a0u.x = hsu[base + offs[0]];
      a0u.y = hsu[base + offs[1]];
      a0u.z = hsu[base + offs[2]];
      a0u.w = hsu[base + offs[3]];
      a1u.x = hsu[base + offs[4]];
      a1u.y = hsu[base + offs[5]];
      a1u.z = hsu[base + offs[6]];
      a1u.w = hsu[base + offs[7]];
      if (q == 0) {  // only k32 32..35 real in K-step 2
        a2u.x = hsu[base + offs[8]];
        a2u.y = hsu[base + offs[9]];
        a2u.z = hsu[base + offs[10]];
        a2u.w = hsu[base + offs[11]];
      }
      f32x4 acc = {0.f, 0.f, 0.f, 0.f};
      acc = __builtin_amdgcn_mfma_f32_16x16x32_f16(as_f16x8(a0u), as_f16x8(bu0), acc, 0, 0, 0);
      acc = __builtin_amdgcn_mfma_f32_16x16x32_f16(as_f16x8(a1u), as_f16x8(bu1), acc, 0, 0, 0);
      acc = __builtin_amdgcn_mfma_f32_16x16x32_f16(as_f16x8(a2u), as_f16x8(bu2), acc, 0, 0, 0);
      float mx = fmaxf(fmaxf(acc[0], acc[1]), fmaxf(acc[2], acc[3]));
      float fv = fmaxf(mx + b2v, 0.f);  // f[oc=l&15][f-pixel q of patch p_l]
      fsh[p_l * (2 * FSTR) + l] = (_Float16)fv;
    }
    __syncthreads();
    // reduce: thread t<196 -> (row=p_l, ot); 32 fdot2 over 64 lanes
    if (tid < 196) {
      int row = tid >> 2, ot = tid & 3;
      const unsigned* fr = fsu + row * FSTR;
      float acc = 0.f;
#pragma unroll
      for (int i = 0; i < 32; ++i)
        acc = fdot2_(as_h2(fr[i]), as_h2(wps[i * 4 + ot]), acc);
      pfl[row * 4 + ot] = acc + bpv;
    }
    __syncthreads();
  }

  // ---- P3: fc1 partial over this tile's 49 patches (float4 gather) ----
  {
    int j = tid >> 2, q4 = tid & 3;
    const float* wrow = w_fc1 + j * 784;
    float acc = 0.f;
#pragma unroll 4
    for (int lp = q4; lp < 49; lp += 4) {
      int Pl = lp / 7, Ql = lp - Pl * 7;
      int gp = (7 * sr + Pl) * 14 + 7 * sc + Ql;  // global patch index
      float4 w4 = *(const float4*)(wrow + gp * 4);
      float4 p4 = *(const float4*)(pfl + lp * 4);
      acc += w4.x * p4.x + w4.y * p4.y + w4.z * p4.z + w4.w * p4.w;
    }
    acc += __shfl_down(acc, 2, 4);
    acc += __shfl_down(acc, 1, 4);
    if (q4 == 0) h1p[((long)b * 4 + tile) * 64 + j] = acc;
  }
}

// -------- k_tail: 1 wave/batch, shuffle-only fc2 + log_softmax --------------
__global__ __launch_bounds__(256) void k_tail(const float* __restrict__ h1p,
                                              const float* __restrict__ b_fc1,
                                              const float* __restrict__ w_fc2,
                                              const float* __restrict__ b_fc2,
                                              float* __restrict__ out) {
  const int l = threadIdx.x & 63;
  const int wv = threadIdx.x >> 6;
  const int b = blockIdx.x * 4 + wv;
  const float* hp = h1p + (long)b * 256;
  float v = b_fc1[l] + hp[l] + hp[64 + l] + hp[128 + l] + hp[192 + l];
  float h = fmaxf(v, 0.f);
  float lg[10];
#pragma unroll
  for (int o = 0; o < 10; ++o) {
    float t = h * w_fc2[o * 64 + l];
#pragma unroll
    for (int off = 32; off; off >>= 1) t += __shfl_xor(t, off);
    lg[o] = t + b_fc2[o];  // every lane holds all 10 logits
  }
  float mx = lg[0];
#pragma unroll
  for (int o = 1; o < 10; ++o) mx = fmaxf(mx, lg[o]);
  float se = 0.f;
#pragma unroll
  for (int o = 0; o < 10; ++o) se += __expf(lg[o] - mx);
  float ls = mx + __logf(se);
#pragma unroll
  for (int o = 0; o < 10; ++o)  // static-index stores (no scratch)
    if (l == o) out[b * 10 + o] = lg[o] - ls;
}

extern "C" void kernel_launch(void* const* d_in, const int* in_sizes, int n_in,
                              void* d_out, int out_size, void* d_ws, size_t ws_size,
                              hipStream_t stream) {
  const float* x = (const float*)d_in[0];
  const float* w1 = (const float*)d_in[1];
  const float* b1 = (const float*)d_in[2];
  const float* w2 = (const float*)d_in[3];
  const float* b2 = (const float*)d_in[4];
  const float* wp = (const float*)d_in[5];
  const float* bp = (const float*)d_in[6];
  const float* wf1 = (const float*)d_in[7];
  const float* bf1 = (const float*)d_in[8];
  const float* wf2 = (const float*)d_in[9];
  const float* bf2 = (const float*)d_in[10];

  float* h1p = (float*)d_ws;  // [512][4][64] = 131072 floats (512 KB)

  k_fused<<<dim3(2048), 256, 0, stream>>>(x, w1, b1, w2, b2, wp, bp, wf1, h1p);
  k_tail<<<dim3(128), 256, 0, stream>>>(h1p, bf1, wf2, bf2, (float*)d_out);
}

// Round 3
// 117.780 us; speedup vs baseline: 1.0315x; 1.0315x over previous
//
#include <hip/hip_runtime.h>

// R19 (resubmit — previous round was an infra failure, no counters returned):
// P2 A-gather 12x ds_read_b32 -> 3x ds_read_b128 via layout change.
//   hsu now pixel-major [30][30][8ch] f16 (16 B/pixel, aligned): k-mapping
//   k = tap*8 + ch (12 tap slots; taps 9..11 dead with B=0). Each lane's
//   K-step A-fragment = one aligned b128 read; P1 writes one b128/task.
//   Conflict-free: pixel stride 30 -> quad = (6*yoff+xoff)%8 uniform.
//   LDS 25.3 KB -> 6 blocks/CU. No q==0 divergence in P2 anymore.
// Post-mortems pinned: (R14) no cross-block device fence; (R15) no long-lived
// VGPR state (spills); (R18) occupancy alone didn't help -> attack per-block
// LDS op count / latency chain (this round). Watch SQ_LDS_BANK_CONFLICT
// (predict 1.9M -> ~0.3M) and k_fused dur (predict ~34 us).

#define FSTR 33  // fsu row stride in u32 (66 f16) -> conflict-free reduce

typedef _Float16 half2_t __attribute__((ext_vector_type(2)));
typedef _Float16 f16x8 __attribute__((ext_vector_type(8)));
typedef float f32x4 __attribute__((ext_vector_type(4)));
typedef float f32x2 __attribute__((ext_vector_type(2)));

__device__ __forceinline__ unsigned pack_f16(float a, float b) {
  union { half2_t h; unsigned u; } z;
  z.h[0] = (_Float16)a;
  z.h[1] = (_Float16)b;
  return z.u;
}

__device__ __forceinline__ half2_t as_h2(unsigned u) {
  union { unsigned u; half2_t h; } z;
  z.u = u;
  return z.h;
}

__device__ __forceinline__ f16x8 as_f16x8(uint4 u) {
  union { uint4 u; f16x8 f; } z;
  z.u = u;
  return z.f;
}

__device__ __forceinline__ float fdot2_(half2_t a, half2_t b, float c) {
#if __has_builtin(__builtin_amdgcn_fdot2)
  return __builtin_amdgcn_fdot2(a, b, c, false);
#else
  return c + (float)a[0] * (float)b[0] + (float)a[1] * (float)b[1];
#endif
}

__global__ __launch_bounds__(256, 6) void k_fused(
    const float* __restrict__ x, const float* __restrict__ w1,
    const float* __restrict__ b1, const float* __restrict__ w2,
    const float* __restrict__ b2, const float* __restrict__ wp,
    const float* __restrict__ bp, const float* __restrict__ w_fc1,
    float* __restrict__ h1p) {
  // hsu: [row 0..29][col 0..29][ch 0..7] f16, 4 u32 per pixel (16B aligned)
  __shared__ __align__(16) unsigned hsu[3600];   // 14.4 KB
  __shared__ __align__(16) unsigned bwl[768];    // 3.0 KB: [oc16][tap12][w4]
  __shared__ __align__(16) unsigned wps[128];    // 0.5 KB wp pairs [i][ot]
  __shared__ __align__(16) unsigned fsu[49 * FSTR];  // 6.3 KB (f16 rows)
  __shared__ __align__(16) float pfl[196];       // 0.8 KB
  const int tid = threadIdx.x;
  const int b = blockIdx.x >> 2;
  const int tile = blockIdx.x & 3;
  const int sr = tile >> 1;
  const int sc = tile & 1;
  const int l = tid & 63;
  const int wv = __builtin_amdgcn_readfirstlane(tid >> 6);  // wave id 0..3
  const float* xb = x + (long)b * 12544;
  const float bpv = bp[tid & 3];

  for (int i = tid; i < 3600; i += 256) hsu[i] = 0u;
  // Pack conv2 weights: bwl[((oc*12 + tap)*4 + w)] = f16pair(ch 2w, 2w+1).
  // Taps 9..11 are dead K-slots (zero) so A can read any valid address there.
  for (int t = tid; t < 768; t += 256) {
    int oc = t / 48, rem = t - oc * 48;
    int tap = rem >> 2, w = rem & 3;
    unsigned v = 0u;
    if (tap < 9)
      v = pack_f16(w2[(oc * 8 + 2 * w) * 9 + tap],
                   w2[(oc * 8 + 2 * w + 1) * 9 + tap]);
    bwl[t] = v;
  }
  // Pack patch weights: wps[i*4+ot] = f16pair over lanes (2i, 2i+1) for ot.
  if (tid < 128) {
    int i = tid >> 2, ot = tid & 3;
    int l0 = 2 * i, l1 = 2 * i + 1;
    wps[tid] = pack_f16(wp[ot * 64 + (l0 & 15) * 4 + (l0 >> 4)],
                        wp[ot * 64 + (l1 & 15) * 4 + (l1 >> 4)]);
  }
  __syncthreads();

  // ---- P1: conv1(1->8)+bias+relu+maxpool2 (packed f32) -> f16 LDS tile ----
  // tile: 30x30 pooled-h cells, (r,c) -> global (28*sr-1+r, 28*sc-1+c)
  for (int task = tid; task < 900; task += 256) {
    int r = task / 30, c = task - r * 30;
    int gr = 28 * sr - 1 + r;
    int gc = 28 * sc - 1 + c;
    if ((unsigned)gr >= 56u || (unsigned)gc >= 56u) continue;
    float win[4][4];
    int iy0 = 2 * gr - 1, ix0 = 2 * gc - 1;
    if (gr >= 1 && gr <= 54 && gc >= 1 && gc <= 54) {
      // interior fast path: all 16 taps in-bounds, no cndmask chains
      const float* xp = xb + iy0 * 112 + ix0;
#pragma unroll
      for (int rr = 0; rr < 4; ++rr)
#pragma unroll
        for (int qq = 0; qq < 4; ++qq)
          win[rr][qq] = xp[rr * 112 + qq];
    } else {
#pragma unroll
      for (int rr = 0; rr < 4; ++rr) {
        int iy = iy0 + rr;
        bool yok = (unsigned)iy < 112u;
#pragma unroll
        for (int qq = 0; qq < 4; ++qq) {
          int ix = ix0 + qq;
          win[rr][qq] = (yok && (unsigned)ix < 112u) ? xb[iy * 112 + ix] : 0.f;
        }
      }
    }
    float hv[8];
#pragma unroll
    for (int ch = 0; ch < 8; ++ch) {
      f32x2 sA = {0.f, 0.f};  // (s00, s01)
      f32x2 sB = {0.f, 0.f};  // (s10, s11)
#pragma unroll
      for (int ty = 0; ty < 3; ++ty)
#pragma unroll
        for (int tx = 0; tx < 3; ++tx) {
          float wk = w1[ch * 9 + ty * 3 + tx];
          f32x2 wkk = {wk, wk};
          f32x2 xa = {win[ty][tx], win[ty][tx + 1]};
          f32x2 xb2 = {win[ty + 1][tx], win[ty + 1][tx + 1]};
          sA = __builtin_elementwise_fma(xa, wkk, sA);
          sB = __builtin_elementwise_fma(xb2, wkk, sB);
        }
      f32x2 sm = __builtin_elementwise_max(sA, sB);
      float m = fmaxf(sm.x, sm.y);
      hv[ch] = fmaxf(m + b1[ch], 0.f);
    }
    uint4 hw;
    hw.x = pack_f16(hv[0], hv[1]);
    hw.y = pack_f16(hv[2], hv[3]);
    hw.z = pack_f16(hv[4], hv[5]);
    hw.w = pack_f16(hv[6], hv[7]);
    *(uint4*)(hsu + (r * 30 + c) * 4) = hw;  // one aligned b128 store
  }
  __syncthreads();

  // ---- P2: conv2+pool+relu via MFMA; fv -> fsu; patch reduce -> pfl ----
  {
    const int q = l >> 4;  // k-quarter / fmem role (a=q>>1, b=q&1)
    const int yoff = 2 * ((l >> 3) & 1) + ((l >> 1) & 1);  // 2a+dy (row m)
    const int xoff = 2 * ((l >> 2) & 1) + (l & 1);         // 2b+dx
    int poff[3];
#pragma unroll
    for (int kk = 0; kk < 3; ++kk) {
      int t = kk * 4 + q;
      int tt = t < 9 ? t : 8;  // dead taps alias tap 8 (B there is zero)
      int ty = tt / 3, tx = tt - ty * 3;
      poff[kk] = ((yoff + ty) * 30 + xoff + tx) * 4;  // u32 units
    }
    uint4 bu0 = *(const uint4*)(bwl + ((l & 15) * 12 + 0 + q) * 4);
    uint4 bu1 = *(const uint4*)(bwl + ((l & 15) * 12 + 4 + q) * 4);
    uint4 bu2 = *(const uint4*)(bwl + ((l & 15) * 12 + 8 + q) * 4);
    const float b2v = b2[l & 15];
    _Float16* fsh = (_Float16*)fsu;

#pragma unroll 2
    for (int p_l = wv; p_l < 49; p_l += 4) {  // 7x7 local patches
      int py = p_l / 7, px = p_l - py * 7;
      int pb = 480 * py + 16 * px;  // u32 offset of patch origin pixel
      uint4 a0u = *(const uint4*)(hsu + pb + poff[0]);
      uint4 a1u = *(const uint4*)(hsu + pb + poff[1]);
      uint4 a2u = *(const uint4*)(hsu + pb + poff[2]);
      f32x4 acc = {0.f, 0.f, 0.f, 0.f};
      acc = __builtin_amdgcn_mfma_f32_16x16x32_f16(as_f16x8(a0u), as_f16x8(bu0), acc, 0, 0, 0);
      acc = __builtin_amdgcn_mfma_f32_16x16x32_f16(as_f16x8(a1u), as_f16x8(bu1), acc, 0, 0, 0);
      acc = __builtin_amdgcn_mfma_f32_16x16x32_f16(as_f16x8(a2u), as_f16x8(bu2), acc, 0, 0, 0);
      float mx = fmaxf(fmaxf(acc[0], acc[1]), fmaxf(acc[2], acc[3]));
      float fv = fmaxf(mx + b2v, 0.f);  // f[oc=l&15][f-pixel q of patch p_l]
      fsh[p_l * (2 * FSTR) + l] = (_Float16)fv;
    }
    __syncthreads();
    // reduce: thread t<196 -> (row=p_l, ot); 32 fdot2 over 64 lanes
    if (tid < 196) {
      int row = tid >> 2, ot = tid & 3;
      const unsigned* fr = fsu + row * FSTR;
      float acc = 0.f;
#pragma unroll
      for (int i = 0; i < 32; ++i)
        acc = fdot2_(as_h2(fr[i]), as_h2(wps[i * 4 + ot]), acc);
      pfl[row * 4 + ot] = acc + bpv;
    }
    __syncthreads();
  }

  // ---- P3: fc1 partial over this tile's 49 patches (float4 gather) ----
  {
    int j = tid >> 2, q4 = tid & 3;
    const float* wrow = w_fc1 + j * 784;
    float acc = 0.f;
#pragma unroll 4
    for (int lp = q4; lp < 49; lp += 4) {
      int Pl = lp / 7, Ql = lp - Pl * 7;
      int gp = (7 * sr + Pl) * 14 + 7 * sc + Ql;  // global patch index
      float4 w4 = *(const float4*)(wrow + gp * 4);
      float4 p4 = *(const float4*)(pfl + lp * 4);
      acc += w4.x * p4.x + w4.y * p4.y + w4.z * p4.z + w4.w * p4.w;
    }
    acc += __shfl_down(acc, 2, 4);
    acc += __shfl_down(acc, 1, 4);
    if (q4 == 0) h1p[((long)b * 4 + tile) * 64 + j] = acc;
  }
}

// -------- k_tail: 1 wave/batch, shuffle-only fc2 + log_softmax --------------
__global__ __launch_bounds__(256) void k_tail(const float* __restrict__ h1p,
                                              const float* __restrict__ b_fc1,
                                              const float* __restrict__ w_fc2,
                                              const float* __restrict__ b_fc2,
                                              float* __restrict__ out) {
  const int l = threadIdx.x & 63;
  const int wv = threadIdx.x >> 6;
  const int b = blockIdx.x * 4 + wv;
  const float* hp = h1p + (long)b * 256;
  float v = b_fc1[l] + hp[l] + hp[64 + l] + hp[128 + l] + hp[192 + l];
  float h = fmaxf(v, 0.f);
  float lg[10];
#pragma unroll
  for (int o = 0; o < 10; ++o) {
    float t = h * w_fc2[o * 64 + l];
#pragma unroll
    for (int off = 32; off; off >>= 1) t += __shfl_xor(t, off);
    lg[o] = t + b_fc2[o];  // every lane holds all 10 logits
  }
  float mx = lg[0];
#pragma unroll
  for (int o = 1; o < 10; ++o) mx = fmaxf(mx, lg[o]);
  float se = 0.f;
#pragma unroll
  for (int o = 0; o < 10; ++o) se += __expf(lg[o] - mx);
  float ls = mx + __logf(se);
#pragma unroll
  for (int o = 0; o < 10; ++o)  // static-index stores (no scratch)
    if (l == o) out[b * 10 + o] = lg[o] - ls;
}

extern "C" void kernel_launch(void* const* d_in, const int* in_sizes, int n_in,
                              void* d_out, int out_size, void* d_ws, size_t ws_size,
                              hipStream_t stream) {
  const float* x = (const float*)d_in[0];
  const float* w1 = (const float*)d_in[1];
  const float* b1 = (const float*)d_in[2];
  const float* w2 = (const float*)d_in[3];
  const float* b2 = (const float*)d_in[4];
  const float* wp = (const float*)d_in[5];
  const float* bp = (const float*)d_in[6];
  const float* wf1 = (const float*)d_in[7];
  const float* bf1 = (const float*)d_in[8];
  const float* wf2 = (const float*)d_in[9];
  const float* bf2 = (const float*)d_in[10];

  float* h1p = (float*)d_ws;  // [512][4][64] = 131072 floats (512 KB)

  k_fused<<<dim3(2048), 256, 0, stream>>>(x, w1, b1, w2, b2, wp, bp, wf1, h1p);
  k_tail<<<dim3(128), 256, 0, stream>>>(h1p, bf1, wf2, bf2, (float*)d_out);
}

// Round 4
// 116.408 us; speedup vs baseline: 1.0437x; 1.0118x over previous
//
#include <hip/hip_runtime.h>

// R20: single kernel, one block per image (512 blocks x 1024 thr), NO workspace.
//   Motivation: measured dur ~= 43us ws-poison fill + ~40us k_fused + k_tail +
//   launch gaps. Killing d_ws + second launch attacks the non-kernel ~45us.
//   LDS: hsu full-image [58][58][8ch] f16 pixel-major (53.8KB) + bwl 3KB +
//   wps 0.5KB + fsu 98-row chunk 12.9KB + pfl 784 f32 + h1s = 73.7KB
//   -> 2 blocks/CU, 32 waves/CU. VGPR must stay <=64 (launch_bounds 1024,8).
//   Phases: {ring-zero | pack bwl/wps | P1 conv1 3136 tasks} -> barrier ->
//   P2 conv2 MFMA in 2 chunks of 98 patches (fsu reuse, 2 barriers each) ->
//   fc1 (j,q16) 16-way split + shfl reduce -> h1s -> barrier -> wave0 fc2+lsm.
// Pinned: (R14) no cross-block sync; (R15) no long-lived VGPR state;
// (R18) occupancy alone isn't the lever -> this round is structural overhead;
// (R19) pixel-major hsu, k=tap*8+ch, b128 A-reads (kept verbatim).
// Watch: VGPR_Count==64 + scratch traffic => spill, back off to (1024,7);
// k_all >= 45us => lockstep cost exceeded savings, revert split.

#define HS 58    // hsu row stride in pixels (16B each)
#define FSTR 33  // fsu row stride in u32 (66 f16) -> conflict-free reduce

typedef _Float16 half2_t __attribute__((ext_vector_type(2)));
typedef _Float16 f16x8 __attribute__((ext_vector_type(8)));
typedef float f32x4 __attribute__((ext_vector_type(4)));
typedef float f32x2 __attribute__((ext_vector_type(2)));

__device__ __forceinline__ unsigned pack_f16(float a, float b) {
  union { half2_t h; unsigned u; } z;
  z.h[0] = (_Float16)a;
  z.h[1] = (_Float16)b;
  return z.u;
}

__device__ __forceinline__ half2_t as_h2(unsigned u) {
  union { unsigned u; half2_t h; } z;
  z.u = u;
  return z.h;
}

__device__ __forceinline__ f16x8 as_f16x8(uint4 u) {
  union { uint4 u; f16x8 f; } z;
  z.u = u;
  return z.f;
}

__device__ __forceinline__ float fdot2_(half2_t a, half2_t b, float c) {
#if __has_builtin(__builtin_amdgcn_fdot2)
  return __builtin_amdgcn_fdot2(a, b, c, false);
#else
  return c + (float)a[0] * (float)b[0] + (float)a[1] * (float)b[1];
#endif
}

__global__ __launch_bounds__(1024, 8) void k_all(
    const float* __restrict__ x, const float* __restrict__ w1,
    const float* __restrict__ b1, const float* __restrict__ w2,
    const float* __restrict__ b2, const float* __restrict__ wp,
    const float* __restrict__ bp, const float* __restrict__ w_fc1,
    const float* __restrict__ b_fc1, const float* __restrict__ w_fc2,
    const float* __restrict__ b_fc2, float* __restrict__ out) {
  // hsu: [hr 0..57][hc 0..57][ch 0..7] f16; hr = pooled_row+1 (ring = zero pad)
  __shared__ __align__(16) unsigned hsu[HS * HS * 4];  // 53.8 KB
  __shared__ __align__(16) unsigned bwl[768];          // 3.0 KB [oc16][tap12][w4]
  __shared__ __align__(16) unsigned wps[128];          // 0.5 KB wp pairs [i][ot]
  __shared__ __align__(16) unsigned fsu[98 * FSTR];    // 12.9 KB (f16 rows)
  __shared__ __align__(16) float pfl[784];             // 3.1 KB
  __shared__ float h1s[64];
  const int tid = threadIdx.x;
  const int b = blockIdx.x;
  const int l = tid & 63;
  const int wv = __builtin_amdgcn_readfirstlane(tid >> 6);  // wave id 0..15
  const float* xb = x + (long)b * 12544;
  const float bpv = bp[tid & 3];

  // ---- setup (same barrier region as P1: disjoint LDS writes) ----
  if (tid < 228) {  // zero the padding ring (P1 writes interior only)
    int i = tid, hr, hc;
    if (i < 58) { hr = 0; hc = i; }
    else if (i < 116) { hr = 57; hc = i - 58; }
    else if (i < 172) { hr = i - 115; hc = 0; }
    else { hr = i - 171; hc = 57; }
    *(uint4*)(hsu + (hr * HS + hc) * 4) = make_uint4(0u, 0u, 0u, 0u);
  }
  // Pack conv2 weights: bwl[(oc*12 + tap)*4 + w] = f16pair(ch 2w, 2w+1).
  // Taps 9..11 are dead K-slots (zero B) so A may read any valid address.
  if (tid < 768) {
    int t = tid, oc = t / 48, rem = t - oc * 48;
    int tap = rem >> 2, w = rem & 3;
    unsigned v = 0u;
    if (tap < 9)
      v = pack_f16(w2[(oc * 8 + 2 * w) * 9 + tap],
                   w2[(oc * 8 + 2 * w + 1) * 9 + tap]);
    bwl[t] = v;
  }
  // Pack patch weights: wps[i*4+ot] = f16pair over lanes (2i, 2i+1) for ot.
  if (tid >= 768 && tid < 896) {
    int t = tid - 768;
    int i = t >> 2, ot = t & 3;
    int l0 = 2 * i, l1 = 2 * i + 1;
    wps[t] = pack_f16(wp[ot * 64 + (l0 & 15) * 4 + (l0 >> 4)],
                      wp[ot * 64 + (l1 & 15) * 4 + (l1 >> 4)]);
  }

  // ---- P1: conv1(1->8)+bias+relu+maxpool2 -> f16 pixel-major LDS tile ----
  for (int task = tid; task < 3136; task += 1024) {
    int gr = task / 56, gc = task - gr * 56;  // pooled coords 0..55
    float win[4][4];
    int iy0 = 2 * gr - 1, ix0 = 2 * gc - 1;
    if (gr >= 1 && gr <= 54 && gc >= 1 && gc <= 54) {
      const float* xp = xb + iy0 * 112 + ix0;  // interior: all in-bounds
#pragma unroll
      for (int rr = 0; rr < 4; ++rr)
#pragma unroll
        for (int qq = 0; qq < 4; ++qq)
          win[rr][qq] = xp[rr * 112 + qq];
    } else {
#pragma unroll
      for (int rr = 0; rr < 4; ++rr) {
        int iy = iy0 + rr;
        bool yok = (unsigned)iy < 112u;
#pragma unroll
        for (int qq = 0; qq < 4; ++qq) {
          int ix = ix0 + qq;
          win[rr][qq] = (yok && (unsigned)ix < 112u) ? xb[iy * 112 + ix] : 0.f;
        }
      }
    }
    float hv[8];
#pragma unroll
    for (int ch = 0; ch < 8; ++ch) {
      f32x2 sA = {0.f, 0.f};
      f32x2 sB = {0.f, 0.f};
#pragma unroll
      for (int ty = 0; ty < 3; ++ty)
#pragma unroll
        for (int tx = 0; tx < 3; ++tx) {
          float wk = w1[ch * 9 + ty * 3 + tx];
          f32x2 wkk = {wk, wk};
          f32x2 xa = {win[ty][tx], win[ty][tx + 1]};
          f32x2 xb2 = {win[ty + 1][tx], win[ty + 1][tx + 1]};
          sA = __builtin_elementwise_fma(xa, wkk, sA);
          sB = __builtin_elementwise_fma(xb2, wkk, sB);
        }
      f32x2 sm = __builtin_elementwise_max(sA, sB);
      float m = fmaxf(sm.x, sm.y);
      hv[ch] = fmaxf(m + b1[ch], 0.f);
    }
    uint4 hw;
    hw.x = pack_f16(hv[0], hv[1]);
    hw.y = pack_f16(hv[2], hv[3]);
    hw.z = pack_f16(hv[4], hv[5]);
    hw.w = pack_f16(hv[6], hv[7]);
    *(uint4*)(hsu + ((gr + 1) * HS + gc + 1) * 4) = hw;  // one b128 store
  }
  __syncthreads();

  // ---- P2: conv2+pool+relu via MFMA; 2 chunks of 98 patches ----
  {
    const int q = l >> 4;  // k-quarter / f-pixel role (a=q>>1, b=q&1)
    const int yoff = 2 * ((l >> 3) & 1) + ((l >> 1) & 1);  // 2a+dy
    const int xoff = 2 * ((l >> 2) & 1) + (l & 1);         // 2b+dx
    int poff[3];
#pragma unroll
    for (int kk = 0; kk < 3; ++kk) {
      int t = kk * 4 + q;
      int tt = t < 9 ? t : 8;  // dead taps alias tap 8 (B there is zero)
      int ty = tt / 3, tx = tt - ty * 3;
      poff[kk] = ((yoff + ty) * HS + xoff + tx) * 4;  // u32 units
    }
    uint4 bu0 = *(const uint4*)(bwl + ((l & 15) * 12 + 0 + q) * 4);
    uint4 bu1 = *(const uint4*)(bwl + ((l & 15) * 12 + 4 + q) * 4);
    uint4 bu2 = *(const uint4*)(bwl + ((l & 15) * 12 + 8 + q) * 4);
    const float b2v = b2[l & 15];
    _Float16* fsh = (_Float16*)fsu;

    for (int c = 0; c < 2; ++c) {
#pragma unroll 2
      for (int p_l = wv; p_l < 98; p_l += 16) {
        int p = c * 98 + p_l;
        int py = p / 14, px = p - py * 14;
        int pb = (4 * py * HS + 4 * px) * 4;  // u32 offset of patch origin
        uint4 a0u = *(const uint4*)(hsu + pb + poff[0]);
        uint4 a1u = *(const uint4*)(hsu + pb + poff[1]);
        uint4 a2u = *(const uint4*)(hsu + pb + poff[2]);
        f32x4 acc = {0.f, 0.f, 0.f, 0.f};
        acc = __builtin_amdgcn_mfma_f32_16x16x32_f16(as_f16x8(a0u), as_f16x8(bu0), acc, 0, 0, 0);
        acc = __builtin_amdgcn_mfma_f32_16x16x32_f16(as_f16x8(a1u), as_f16x8(bu1), acc, 0, 0, 0);
        acc = __builtin_amdgcn_mfma_f32_16x16x32_f16(as_f16x8(a2u), as_f16x8(bu2), acc, 0, 0, 0);
        float mx = fmaxf(fmaxf(acc[0], acc[1]), fmaxf(acc[2], acc[3]));
        float fv = fmaxf(mx + b2v, 0.f);  // f[oc=l&15][f-pixel q of patch p]
        fsh[p_l * (2 * FSTR) + l] = (_Float16)fv;
      }
      __syncthreads();
      // chunk reduce: thread t<392 -> (row, ot); 32 fdot2 over 64 f16
      if (tid < 392) {
        int row = tid >> 2, ot = tid & 3;
        const unsigned* fr = fsu + row * FSTR;
        float acc = 0.f;
#pragma unroll
        for (int i = 0; i < 32; ++i)
          acc = fdot2_(as_h2(fr[i]), as_h2(wps[i * 4 + ot]), acc);
        pfl[(c * 98 + row) * 4 + ot] = acc + bpv;
      }
      __syncthreads();
    }
  }

  // ---- fc1: thread (j = tid>>4, q16 = tid&15); 16-way K-split ----
  {
    int j = tid >> 4, q16 = tid & 15;
    const float* wrow = w_fc1 + j * 784;
    float acc = 0.f;
    for (int lp = q16; lp < 196; lp += 16) {
      float4 w4 = *(const float4*)(wrow + lp * 4);
      float4 p4 = *(const float4*)(pfl + lp * 4);
      acc += w4.x * p4.x + w4.y * p4.y + w4.z * p4.z + w4.w * p4.w;
    }
    acc += __shfl_down(acc, 8, 16);
    acc += __shfl_down(acc, 4, 16);
    acc += __shfl_down(acc, 2, 16);
    acc += __shfl_down(acc, 1, 16);
    if (q16 == 0) h1s[j] = fmaxf(acc + b_fc1[j], 0.f);
  }
  __syncthreads();

  // ---- fc2 + log_softmax: wave 0 only (shuffle-reduce, no LDS temps) ----
  if (wv == 0) {
    float h = h1s[l];
    float lg[10];
#pragma unroll
    for (int o = 0; o < 10; ++o) {
      float t = h * w_fc2[o * 64 + l];
#pragma unroll
      for (int off = 32; off; off >>= 1) t += __shfl_xor(t, off);
      lg[o] = t + b_fc2[o];  // every lane holds all 10 logits
    }
    float mx = lg[0];
#pragma unroll
    for (int o = 1; o < 10; ++o) mx = fmaxf(mx, lg[o]);
    float se = 0.f;
#pragma unroll
    for (int o = 0; o < 10; ++o) se += __expf(lg[o] - mx);
    float ls = mx + __logf(se);
#pragma unroll
    for (int o = 0; o < 10; ++o)  // static-index stores (no scratch)
      if (l == o) out[b * 10 + o] = lg[o] - ls;
  }
}

extern "C" void kernel_launch(void* const* d_in, const int* in_sizes, int n_in,
                              void* d_out, int out_size, void* d_ws, size_t ws_size,
                              hipStream_t stream) {
  const float* x = (const float*)d_in[0];
  const float* w1 = (const float*)d_in[1];
  const float* b1 = (const float*)d_in[2];
  const float* w2 = (const float*)d_in[3];
  const float* b2 = (const float*)d_in[4];
  const float* wp = (const float*)d_in[5];
  const float* bp = (const float*)d_in[6];
  const float* wf1 = (const float*)d_in[7];
  const float* bf1 = (const float*)d_in[8];
  const float* wf2 = (const float*)d_in[9];
  const float* bf2 = (const float*)d_in[10];
  (void)d_ws; (void)ws_size;  // workspace unused: no h1p, no combine kernel

  k_all<<<dim3(512), 1024, 0, stream>>>(x, w1, b1, w2, b2, wp, bp, wf1, bf1,
                                        wf2, bf2, (float*)d_out);
}

// Round 9
// 116.060 us; speedup vs baseline: 1.0468x; 1.0030x over previous
//
#include <hip/hip_runtime.h>

// R24 = R23 + THE actual fix: projection K=64 split into two K=32 MFMAs
// needs TWO B-frags — MFMA#2 (k 32..63) must use wp[oc][32+q*8+j], not the
// same wpf as MFMA#1. R22/R23 failed with IDENTICAL absmax 0.234 (deterministic,
// fence-insensitive) because the upper 32 patch features were weighted by the
// lower 32 wp entries. A-side (ar vs ar+16) was already correct.
// Kept from R23: lgkmcnt(0)+sched_barrier fence around the type-punned
// wave-local fsu handoff (TBAA hazard, cheap insurance) and RNE packing.
// Structure (R21): 1 block = 1 image, 1024 thr, grid 512, no workspace.
//   setup {ring-zero hsu, pack bwl} | P1 conv1+relu+pool (float4 loads,
//   b128 store) | BARRIER | P2 per-wave: conv2 via 3xMFMA -> fsu rows ->
//   in-wave MFMA patch-projection -> pfl | BARRIER | fc1 16-way K-split |
//   BARRIER | wave0 fc2+log_softmax.
// Pinned: (R14) no cross-block sync; (R15) no long-lived VGPR state;
// (R18) occupancy not the lever; (R19) pixel-major hsu, k=tap*8+ch;
// (R20) ws poison fill ~43.5us unconditional; (R22/23) split-K MFMA needs
// per-K-step B-frags — check EVERY operand of EVERY new MFMA vs layout.
// Predict: passes (absmax ~0.0156), k_all ~28-33us, total ~104-108us.
// If passes at ~116us: barrier-elimination thesis dead -> measurement round.

#define HS 58    // hsu row stride in pixels (16B each)
#define FS 72    // fsu row stride in f16 (144B; 36 u32 ≡ 4 mod 32)
#define FSW 36   // fsu row stride in u32

typedef _Float16 half2_t __attribute__((ext_vector_type(2)));
typedef _Float16 f16x8 __attribute__((ext_vector_type(8)));
typedef float f32x4 __attribute__((ext_vector_type(4)));
typedef float f32x2 __attribute__((ext_vector_type(2)));
typedef float f32x4u __attribute__((ext_vector_type(4), aligned(4)));

__device__ __forceinline__ unsigned pack_f16(float a, float b) {
  union { half2_t h; unsigned u; } z;
  z.h[0] = (_Float16)a;  // RNE
  z.h[1] = (_Float16)b;
  return z.u;
}

__device__ __forceinline__ f16x8 as_f16x8(uint4 u) {
  union { uint4 u; f16x8 f; } z;
  z.u = u;
  return z.f;
}

__global__ __launch_bounds__(1024, 8) void k_all(
    const float* __restrict__ x, const float* __restrict__ w1,
    const float* __restrict__ b1, const float* __restrict__ w2,
    const float* __restrict__ b2, const float* __restrict__ wp,
    const float* __restrict__ bp, const float* __restrict__ w_fc1,
    const float* __restrict__ b_fc1, const float* __restrict__ w_fc2,
    const float* __restrict__ b_fc2, float* __restrict__ out) {
  // hsu: [hr 0..57][hc 0..57][ch 0..7] f16; hr = pooled_row+1 (ring = zero)
  __shared__ __align__(16) unsigned hsu[HS * HS * 4];  // 53.8 KB
  __shared__ __align__(16) unsigned bwl[768];          // 3.0 KB [oc16][tap12][w4]
  __shared__ __align__(16) unsigned fsu[122 * FSW];    // 17.6 KB f16 K-major rows
  __shared__ __align__(16) float pfl[784];             // 3.1 KB
  __shared__ float h1s[64];
  const int tid = threadIdx.x;
  const int b = blockIdx.x;
  const int l = tid & 63;
  const int wv = __builtin_amdgcn_readfirstlane(tid >> 6);  // wave id 0..15
  const float* xb = x + (long)b * 12544;

  // ---- setup (same barrier region as P1: disjoint LDS writes) ----
  if (tid < 228) {  // zero the padding ring (P1 writes interior only)
    int i = tid, hr, hc;
    if (i < 58) { hr = 0; hc = i; }
    else if (i < 116) { hr = 57; hc = i - 58; }
    else if (i < 172) { hr = i - 115; hc = 0; }
    else { hr = i - 171; hc = 57; }
    *(uint4*)(hsu + (hr * HS + hc) * 4) = make_uint4(0u, 0u, 0u, 0u);
  }
  // Pack conv2 weights: bwl[(oc*12 + tap)*4 + w] = f16pair(ch 2w, 2w+1).
  // Taps 9..11 are dead K-slots (zero B) so A may read any valid address.
  if (tid < 768) {
    int t = tid, oc = t / 48, rem = t - oc * 48;
    int tap = rem >> 2, w = rem & 3;
    unsigned v = 0u;
    if (tap < 9)
      v = pack_f16(w2[(oc * 8 + 2 * w) * 9 + tap],
                   w2[(oc * 8 + 2 * w + 1) * 9 + tap]);
    bwl[t] = v;
  }

  // ---- P1: conv1(1->8)+bias+relu+maxpool2 -> f16 pixel-major LDS tile ----
  for (int task = tid; task < 3136; task += 1024) {
    int gr = task / 56, gc = task - gr * 56;  // pooled coords 0..55
    float win[4][4];
    int iy0 = 2 * gr - 1, ix0 = 2 * gc - 1;
    if (gr >= 1 && gr <= 54 && gc >= 1 && gc <= 54) {
      const float* xp = xb + iy0 * 112 + ix0;  // interior: all in-bounds
#pragma unroll
      for (int rr = 0; rr < 4; ++rr) {
        f32x4u v = *(const f32x4u*)(xp + rr * 112);  // unaligned dwordx4
        win[rr][0] = v.x; win[rr][1] = v.y; win[rr][2] = v.z; win[rr][3] = v.w;
      }
    } else {
#pragma unroll
      for (int rr = 0; rr < 4; ++rr) {
        int iy = iy0 + rr;
        bool yok = (unsigned)iy < 112u;
#pragma unroll
        for (int qq = 0; qq < 4; ++qq) {
          int ix = ix0 + qq;
          win[rr][qq] = (yok && (unsigned)ix < 112u) ? xb[iy * 112 + ix] : 0.f;
        }
      }
    }
    float hv[8];
#pragma unroll
    for (int ch = 0; ch < 8; ++ch) {
      f32x2 sA = {0.f, 0.f};
      f32x2 sB = {0.f, 0.f};
#pragma unroll
      for (int ty = 0; ty < 3; ++ty)
#pragma unroll
        for (int tx = 0; tx < 3; ++tx) {
          float wk = w1[ch * 9 + ty * 3 + tx];
          f32x2 wkk = {wk, wk};
          f32x2 xa = {win[ty][tx], win[ty][tx + 1]};
          f32x2 xb2 = {win[ty + 1][tx], win[ty + 1][tx + 1]};
          sA = __builtin_elementwise_fma(xa, wkk, sA);
          sB = __builtin_elementwise_fma(xb2, wkk, sB);
        }
      f32x2 sm = __builtin_elementwise_max(sA, sB);
      float m = fmaxf(sm.x, sm.y);
      hv[ch] = fmaxf(m + b1[ch], 0.f);
    }
    uint4 hw;
    hw.x = pack_f16(hv[0], hv[1]);
    hw.y = pack_f16(hv[2], hv[3]);
    hw.z = pack_f16(hv[4], hv[5]);
    hw.w = pack_f16(hv[6], hv[7]);
    *(uint4*)(hsu + ((gr + 1) * HS + gc + 1) * 4) = hw;  // one b128 store
  }
  __syncthreads();  // BARRIER 1 (only barrier before fc1!)

  // ---- P2: conv2+pool+relu via MFMA; wave-local, ZERO barriers ----
  {
    const int q = l >> 4;       // k-quarter / f-pixel role (a=q>>1, b=q&1)
    const int oc = l & 15;      // also: patch-row-in-window for projection
    const int yoff = 2 * ((l >> 3) & 1) + ((l >> 1) & 1);  // 2a+dy
    const int xoff = 2 * ((l >> 2) & 1) + (l & 1);         // 2b+dx
    int poff[3];
#pragma unroll
    for (int kk = 0; kk < 3; ++kk) {
      int t = kk * 4 + q;
      int tt = t < 9 ? t : 8;  // dead taps alias tap 8 (B there is zero)
      int ty = tt / 3, tx = tt - ty * 3;
      poff[kk] = ((yoff + ty) * HS + xoff + tx) * 4;  // u32 units
    }
    uint4 bu0 = *(const uint4*)(bwl + (oc * 12 + 0 + q) * 4);
    uint4 bu1 = *(const uint4*)(bwl + (oc * 12 + 4 + q) * 4);
    uint4 bu2 = *(const uint4*)(bwl + (oc * 12 + 8 + q) * 4);
    const float b2v = b2[oc];

    // Projection B-frags: MFMA#1 needs B[k=q*8+j][col=oc] = wp[oc][q*8+j];
    // MFMA#2 (k 32..63 of the K=64 contraction) needs wp[oc][32+q*8+j].
    f16x8 wpf0 = {}, wpf1 = {};
    float bpj = 0.f;
    if (oc < 4) {
      const float* wr = wp + oc * 64 + q * 8;
      float4 wa = *(const float4*)(wr);
      float4 wb = *(const float4*)(wr + 4);
      float4 wc = *(const float4*)(wr + 32);
      float4 wd = *(const float4*)(wr + 36);
      union { unsigned u[4]; f16x8 v; } u0, u1;
      u0.u[0] = pack_f16(wa.x, wa.y);
      u0.u[1] = pack_f16(wa.z, wa.w);
      u0.u[2] = pack_f16(wb.x, wb.y);
      u0.u[3] = pack_f16(wb.z, wb.w);
      u1.u[0] = pack_f16(wc.x, wc.y);
      u1.u[1] = pack_f16(wc.z, wc.w);
      u1.u[2] = pack_f16(wd.x, wd.y);
      u1.u[3] = pack_f16(wd.z, wd.w);
      wpf0 = u0.v;
      wpf1 = u1.v;
      bpj = bp[oc];
    }

    _Float16* fsh = (_Float16*)fsu;
    const int NP = (wv < 4) ? 13 : 12;              // patches owned (contig)
    const int G0 = (wv < 4) ? 13 * wv : 12 * wv + 4;
    const int RW = 7 * wv;                          // private fsu row base
    const int npA = (NP + 1) >> 1;

    for (int hlf = 0; hlf < 2; ++hlf) {
      const int np = hlf ? NP - npA : npA;          // 7|6 then 6
      const int g0 = hlf ? G0 + npA : G0;
      for (int i = 0; i < np; ++i) {
        int p = g0 + i;
        int py = p / 14, px = p - py * 14;
        int pb = (4 * py * HS + 4 * px) * 4;  // u32 offset of patch origin
        uint4 a0u = *(const uint4*)(hsu + pb + poff[0]);
        uint4 a1u = *(const uint4*)(hsu + pb + poff[1]);
        uint4 a2u = *(const uint4*)(hsu + pb + poff[2]);
        f32x4 acc = {0.f, 0.f, 0.f, 0.f};
        acc = __builtin_amdgcn_mfma_f32_16x16x32_f16(as_f16x8(a0u), as_f16x8(bu0), acc, 0, 0, 0);
        acc = __builtin_amdgcn_mfma_f32_16x16x32_f16(as_f16x8(a1u), as_f16x8(bu1), acc, 0, 0, 0);
        acc = __builtin_amdgcn_mfma_f32_16x16x32_f16(as_f16x8(a2u), as_f16x8(bu2), acc, 0, 0, 0);
        float mx = fmaxf(fmaxf(acc[0], acc[1]), fmaxf(acc[2], acc[3]));
        float fv = fmaxf(mx + b2v, 0.f);  // f[oc][f-pixel q] of patch p
        // K-major row: k = oc*4 + q (patch feature index)
        fsh[(RW + i) * FS + oc * 4 + q] = (_Float16)fv;
      }
      // FENCE: writes above via _Float16*, reads below via unsigned* (TBAA
      // no-alias). Order them; HW same-wave DS ops are in-order.
      asm volatile("s_waitcnt lgkmcnt(0)" ::: "memory");
      __builtin_amdgcn_sched_barrier(0);
      // Wave-local projection: pf[p][ot] = sum_k f[p][k]*wp[ot][k], K=64.
      // A rows RW..RW+15 (rows >= np are neighbor garbage -> unstored).
      const unsigned* ar = fsu + (RW + oc) * FSW + q * 4;
      uint4 pa0 = *(const uint4*)(ar);        // k 0..31 slice
      uint4 pa1 = *(const uint4*)(ar + 16);   // k 32..63 slice
      f32x4 pc = {0.f, 0.f, 0.f, 0.f};
      pc = __builtin_amdgcn_mfma_f32_16x16x32_f16(as_f16x8(pa0), wpf0, pc, 0, 0, 0);
      pc = __builtin_amdgcn_mfma_f32_16x16x32_f16(as_f16x8(pa1), wpf1, pc, 0, 0, 0);
      if (oc < 4) {
#pragma unroll
        for (int i2 = 0; i2 < 4; ++i2) {
          int prow = q * 4 + i2;  // C row = patch within window
          if (prow < np) pfl[(g0 + prow) * 4 + oc] = pc[i2] + bpj;
        }
      }
      // Keep next half's writes below this half's reads (WAR on rows 0..5).
      asm volatile("" ::: "memory");
    }
  }
  __syncthreads();  // BARRIER 2

  // ---- fc1: thread (j = tid>>4, q16 = tid&15); 16-way K-split ----
  {
    int j = tid >> 4, q16 = tid & 15;
    const float* wrow = w_fc1 + j * 784;
    float acc = 0.f;
    for (int lp = q16; lp < 196; lp += 16) {
      float4 w4 = *(const float4*)(wrow + lp * 4);
      float4 p4 = *(const float4*)(pfl + lp * 4);
      acc += w4.x * p4.x + w4.y * p4.y + w4.z * p4.z + w4.w * p4.w;
    }
    acc += __shfl_down(acc, 8, 16);
    acc += __shfl_down(acc, 4, 16);
    acc += __shfl_down(acc, 2, 16);
    acc += __shfl_down(acc, 1, 16);
    if (q16 == 0) h1s[j] = fmaxf(acc + b_fc1[j], 0.f);
  }
  __syncthreads();  // BARRIER 3

  // ---- fc2 + log_softmax: wave 0 only (shuffle-reduce, no LDS temps) ----
  if (wv == 0) {
    float h = h1s[l];
    float lg[10];
#pragma unroll
    for (int o = 0; o < 10; ++o) {
      float t = h * w_fc2[o * 64 + l];
#pragma unroll
      for (int off = 32; off; off >>= 1) t += __shfl_xor(t, off);
      lg[o] = t + b_fc2[o];  // every lane holds all 10 logits
    }
    float mx = lg[0];
#pragma unroll
    for (int o = 1; o < 10; ++o) mx = fmaxf(mx, lg[o]);
    float se = 0.f;
#pragma unroll
    for (int o = 0; o < 10; ++o) se += __expf(lg[o] - mx);
    float ls = mx + __logf(se);
#pragma unroll
    for (int o = 0; o < 10; ++o)  // static-index stores (no scratch)
      if (l == o) out[b * 10 + o] = lg[o] - ls;
  }
}

extern "C" void kernel_launch(void* const* d_in, const int* in_sizes, int n_in,
                              void* d_out, int out_size, void* d_ws, size_t ws_size,
                              hipStream_t stream) {
  const float* x = (const float*)d_in[0];
  const float* w1 = (const float*)d_in[1];
  const float* b1 = (const float*)d_in[2];
  const float* w2 = (const float*)d_in[3];
  const float* b2 = (const float*)d_in[4];
  const float* wp = (const float*)d_in[5];
  const float* bp = (const float*)d_in[6];
  const float* wf1 = (const float*)d_in[7];
  const float* bf1 = (const float*)d_in[8];
  const float* wf2 = (const float*)d_in[9];
  const float* bf2 = (const float*)d_in[10];
  (void)d_ws; (void)ws_size;  // workspace unused

  k_all<<<dim3(512), 1024, 0, stream>>>(x, w1, b1, w2, b2, wp, bp, wf1, bf1,
                                        wf2, bf2, (float*)d_out);
}